// Round 7
// baseline (101.356 us; speedup 1.0000x reference)
//
#include <hip/hip_runtime.h>
#include <math.h>

#define WPB 4                 // waves per block
#define RPB (WPB * 2)         // 2 rays per wave (32 lanes each) -> 8 rays/block

// All per-ray LDS is touched only by its own wave (both halves belong to the wave).
__device__ __forceinline__ void wave_fence() {
    asm volatile("s_waitcnt lgkmcnt(0)" ::: "memory");
    __builtin_amdgcn_wave_barrier();
}

// DPP: dest = src[perm] where source lane valid, else ident.
// row_shr:1/2/4/8 = 0x111/0x112/0x114/0x118, row_bcast15 = 0x142,
// wave_shl1 = 0x130 (lane i <- i+1), wave_shr1 = 0x138 (lane i <- i-1).
template<int CTRL, int RMASK>
__device__ __forceinline__ float dpp_f(float ident, float x) {
    return __int_as_float(__builtin_amdgcn_update_dpp(
        __float_as_int(ident), __float_as_int(x), CTRL, RMASK, 0xF, false));
}
template<int CTRL, int RMASK>
__device__ __forceinline__ int dpp_i(int ident, int x) {
    return __builtin_amdgcn_update_dpp(ident, x, CTRL, RMASK, 0xF, false);
}

// 32-lane (per wave-half) inclusive scans: 4 row-shr steps + bcast15 into rows 1,3
__device__ __forceinline__ float scan32_mul(float x) {
    x *= dpp_f<0x111, 0xF>(1.f, x);
    x *= dpp_f<0x112, 0xF>(1.f, x);
    x *= dpp_f<0x114, 0xF>(1.f, x);
    x *= dpp_f<0x118, 0xF>(1.f, x);
    x *= dpp_f<0x142, 0xA>(1.f, x);
    return x;
}
__device__ __forceinline__ float scan32_add(float x) {
    x += dpp_f<0x111, 0xF>(0.f, x);
    x += dpp_f<0x112, 0xF>(0.f, x);
    x += dpp_f<0x114, 0xF>(0.f, x);
    x += dpp_f<0x118, 0xF>(0.f, x);
    x += dpp_f<0x142, 0xA>(0.f, x);
    return x;
}
__device__ __forceinline__ int scan32_max(int x) {
    x = max(x, dpp_i<0x111, 0xF>(-1, x));
    x = max(x, dpp_i<0x112, 0xF>(-1, x));
    x = max(x, dpp_i<0x114, 0xF>(-1, x));
    x = max(x, dpp_i<0x118, 0xF>(-1, x));
    x = max(x, dpp_i<0x142, 0xA>(-1, x));
    return x;
}
// broadcast lane 31 of each 32-half (ds_swizzle bit-mode: and=0, or=0x1F)
__device__ __forceinline__ float bcast31h(float x) {
    return __int_as_float(__builtin_amdgcn_ds_swizzle(__float_as_int(x), 0x03E0));
}

__device__ __forceinline__ float zof(int k) {   // iter-0 analytic z grid
    return 0.2f + 1.8f * ((float)k * (1.0f / 127.0f));
}

struct Ray { float ox, oy, oz, dx, dy, dz; };

__device__ __forceinline__ float sdf_at(const Ray& rr, float t) {
    float px = fminf(fmaxf(rr.ox + rr.dx * t, -1.f), 1.f);
    float py = fminf(fmaxf(rr.oy + rr.dy * t, -1.f), 1.f);
    float pz = fminf(fmaxf(rr.oz + rr.dz * t, -1.f), 1.f);
    return sqrtf(px * px + py * py + pz * pz) - 0.5f;
}

template<int IT>
__device__ __forceinline__ void run_iter(float2* __restrict__ zs, int* __restrict__ mk,
                                         float4* __restrict__ pl, float* __restrict__ outr,
                                         const int l, const Ray rr)
{
    constexpr int  N = 128 + 32 * IT;   // element count: 128,160,192,224
    constexpr int  R = N / 32;          // per-lane elements: 4,5,6,7 (exact)
    constexpr bool LAST  = (IT == 3);
    constexpr bool FIRST = (IT == 0);
    const float c1 = -(float)(64 << IT) * 1.44269504f;   // A = 2^(c1*pe) = e^(-pe*inv_s)
    const int k0 = l * R;

    // ---- owned elements (analytic on iter 0; packed LDS float2 otherwise) ----
    float ez[R], es[R];
    if constexpr (FIRST) {
        #pragma unroll
        for (int r = 0; r < R; ++r) { ez[r] = zof(k0 + r); es[r] = sdf_at(rr, ez[r]); }
    } else {
        #pragma unroll
        for (int r = 0; r < R; ++r) { float2 v = zs[k0 + r]; ez[r] = v.x; es[r] = v.y; }
    }
    // right neighbor = next lane's first element (lane 31 of a half: its top interval
    // is out of range by construction; all its uses are guarded below)
    const float zend = dpp_f<0x130, 0xF>(0.f, ez[0]);
    const float send = dpp_f<0x130, 0xF>(0.f, es[0]);

    // ---- cos of my last interval -> prev_cos for next lane's r=0 ----
    const float ckL = __fdividef(send - es[R - 1], zend - ez[R - 1] + 1e-5f);
    float cosp = dpp_f<0x138, 0xF>(0.f, ckL);
    cosp = (l == 0) ? 0.f : cosp;                 // reference: prev_cos = 0 at k = 0

    // ---- alpha per interval (algebraic sigmoid: 2 exp2 + 1 div) -> q only ----
    float q[R];
    #pragma unroll
    for (int r = 0; r < R; ++r) {
        const float zk1 = (r == R - 1) ? zend : ez[r + 1];
        const float sk1 = (r == R - 1) ? send : es[r + 1];
        const float ckr = __fdividef(sk1 - es[r], zk1 - ez[r] + 1e-5f);
        float cv = fminf(fminf(cosp, ckr), 0.0f);
        cv = fmaxf(cv, -1000.0f);
        const float mid = 0.5f * (es[r] + sk1);
        const float hd  = 0.5f * (zk1 - ez[r]);
        const float A = __builtin_amdgcn_exp2f(fminf(c1 * (mid - cv * hd), 43.0f));
        const float B = __builtin_amdgcn_exp2f(fminf(c1 * (mid + cv * hd), 43.0f));
        const float A1 = 1.0f + A, B1 = 1.0f + B;
        const float prod = A1 * B1;
        const float al = __fdividef((B - A) + 1e-5f * prod, B1 + 1e-5f * prod);
        float qr = (1.0f - al) + 1e-7f;
        if (r == R - 1) qr = (l == 31) ? 1.0f : qr;   // only invalid interval: (31, R-1)
        q[r] = qr;
        cosp = ckr;
    }

    // ---- exclusive transmittance cumprod (per-half DPP scan) ----
    float P = q[0];
    #pragma unroll
    for (int r = 1; r < R; ++r) P *= q[r];
    const float incP = scan32_mul(P);
    float T = dpp_f<0x138, 0xF>(1.f, incP);
    T = (l == 0) ? 1.0f : T;

    // ---- weights (recover a from q) + exclusive sum scan ----
    float wv[R], L = 0.f;
    #pragma unroll
    for (int r = 0; r < R; ++r) {
        const float a = (1.0f + 1e-7f) - q[r];
        float w_ = fmaf(a, T, 1e-5f);
        if (r == R - 1) w_ = (l == 31) ? 0.f : w_;
        wv[r] = w_;
        L += w_;
        T *= q[r];
    }
    const float incL = scan32_add(L);
    const float S = bcast31h(incL);
    float excL = dpp_f<0x138, 0xF>(0.f, incL);
    excL = (l == 0) ? 0.f : excL;
    const float invS = 1.0f / S;

    // ---- cdf (registers only) + closed-form counts cm[r] = #{j: u_j < cdf[k0+r]} ----
    float ce[R];
    int   cm[R];
    float run = excL;
    #pragma unroll
    for (int r = 0; r < R; ++r) {
        ce[r] = run * invS;
        cm[r] = (int)ceilf(fmaf(ce[r], 32.0f, -0.5f));   // cdf in [0,1] -> in [0,32]
        run += wv[r];
    }
    const int   cmend  = dpp_i<0x130, 0xF>(32, cm[0]);   // lane31 use is guarded
    const float cdfend = dpp_f<0x130, 0xF>(1.f, ce[0]);  // lane31 use is guarded

    // ---- marks + payload: one store pair per nonempty interval ----
    #pragma unroll
    for (int r = 0; r < R; ++r) {
        const int jlo = cm[r];
        const int jhi = (r == R - 1) ? cmend : cm[r + 1];
        bool ne = (jhi > jlo);
        if (r == R - 1) ne = ne && (l != 31);
        if (ne) {
            const int   k   = k0 + r;
            const float cl  = ce[r];
            const float ch  = (r == R - 1) ? cdfend : ce[r + 1];
            const float zk  = ez[r];
            const float zk1 = (r == R - 1) ? zend : ez[r + 1];
            mk[jlo] = (k << 5) | jlo;
            pl[jlo] = make_float4(cl, ch, zk, zk1 - zk);
        }
    }
    wave_fence();   // marks + payload visible before sampling reads

    // ---- lane-parallel sampling: ALL 64 lanes (32 samples per ray half) ----
    int m0 = mk[l];
    if constexpr (!LAST) mk[l] = -1;   // same-lane same-address DS ops are ordered
    const int pack = scan32_max(m0);
    const int kk = pack >> 5, js = pack & 31;
    const float4 p4 = pl[js];          // {cl, ch, zk, dz}
    float denom = p4.y - p4.x;
    denom = (denom < 1e-5f) ? 1.0f : denom;
    const float u = (float)(2 * l + 1) * 0.015625f;
    const float nz = fmaf(__fdividef(u - p4.x, denom), p4.w, p4.z);
    const int pos = kk + 1 + l;        // rank among old + stable index among new
    float ns = 0.f;
    if constexpr (!LAST) ns = sdf_at(rr, nz);

    // ---- in-place scatter (sampling read nothing from zs -> no fence needed) ----
    #pragma unroll
    for (int r = 0; r < R; ++r) {
        const int p = k0 + r + cm[r];
        if constexpr (LAST) { outr[p] = ez[r]; }
        else                { zs[p] = make_float2(ez[r], es[r]); }
    }
    if constexpr (LAST) { outr[pos] = nz; }
    else                { zs[pos] = make_float2(nz, ns); }

    if constexpr (!LAST) wave_fence();   // scatter drained before next iter's loads
}

__global__ __launch_bounds__(WPB * 64) void neus_kernel(
    const float* __restrict__ rays_o, const float* __restrict__ rays_d,
    float* __restrict__ out, int nrays)
{
    __shared__ __align__(16) float2 zsS[RPB][224];
    __shared__ __align__(16) float4 plS[RPB][32];
    __shared__               int    mkS[RPB][32];

    const int tid = threadIdx.x;
    const int rb  = tid >> 5;        // ray slot within block (one per 32-lane half)
    const int l   = tid & 31;        // lane within ray
    const int ray = blockIdx.x * RPB + rb;
    if (ray >= nrays) return;        // safe: no block-wide barriers anywhere

    float2* zs = zsS[rb];
    float4* pl = plS[rb];
    int*    mk = mkS[rb];

    Ray rr;
    rr.ox = rays_o[ray * 3 + 0]; rr.oy = rays_o[ray * 3 + 1]; rr.oz = rays_o[ray * 3 + 2];
    float rx = rays_d[ray * 3 + 0], ry = rays_d[ray * 3 + 1], rz = rays_d[ray * 3 + 2];
    float inv = __fdividef(1.0f, sqrtf(rx * rx + ry * ry + rz * rz) + 1e-8f);
    rr.dx = rx * inv; rr.dy = ry * inv; rr.dz = rz * inv;

    mk[l] = -1;   // drained by iter0's publish fence

    float* outr = out + (size_t)ray * 256;
    run_iter<0>(zs, mk, pl, outr, l, rr);   // fully analytic inputs
    run_iter<1>(zs, mk, pl, outr, l, rr);
    run_iter<2>(zs, mk, pl, outr, l, rr);
    run_iter<3>(zs, mk, pl, outr, l, rr);
}

extern "C" void kernel_launch(void* const* d_in, const int* in_sizes, int n_in,
                              void* d_out, int out_size, void* d_ws, size_t ws_size,
                              hipStream_t stream) {
    const float* rays_o = (const float*)d_in[0];
    const float* rays_d = (const float*)d_in[1];
    float* out = (float*)d_out;
    const int nrays = in_sizes[0] / 3;
    const int blocks = (nrays + RPB - 1) / RPB;
    neus_kernel<<<blocks, WPB * 64, 0, stream>>>(rays_o, rays_d, out, nrays);
}

// Round 8
// 93.563 us; speedup vs baseline: 1.0833x; 1.0833x over previous
//
#include <hip/hip_runtime.h>
#include <math.h>

#define WPB 4                 // waves per block
#define RPB (WPB * 2)         // 2 rays per wave (32 lanes each) -> 8 rays/block

// All per-ray LDS is touched only by its own wave (both halves belong to the wave).
__device__ __forceinline__ void wave_fence() {
    asm volatile("s_waitcnt lgkmcnt(0)" ::: "memory");
    __builtin_amdgcn_wave_barrier();
}

// DPP: dest = src[perm] where source lane valid, else ident.
// row_shr:1/2/4/8 = 0x111/0x112/0x114/0x118, row_bcast15 = 0x142,
// wave_shl1 = 0x130 (lane i <- i+1), wave_shr1 = 0x138 (lane i <- i-1).
template<int CTRL, int RMASK>
__device__ __forceinline__ float dpp_f(float ident, float x) {
    return __int_as_float(__builtin_amdgcn_update_dpp(
        __float_as_int(ident), __float_as_int(x), CTRL, RMASK, 0xF, false));
}
template<int CTRL, int RMASK>
__device__ __forceinline__ int dpp_i(int ident, int x) {
    return __builtin_amdgcn_update_dpp(ident, x, CTRL, RMASK, 0xF, false);
}

// 32-lane (per wave-half) inclusive scans: 4 row-shr steps + bcast15 into rows 1,3
__device__ __forceinline__ float scan32_mul(float x) {
    x *= dpp_f<0x111, 0xF>(1.f, x);
    x *= dpp_f<0x112, 0xF>(1.f, x);
    x *= dpp_f<0x114, 0xF>(1.f, x);
    x *= dpp_f<0x118, 0xF>(1.f, x);
    x *= dpp_f<0x142, 0xA>(1.f, x);
    return x;
}
__device__ __forceinline__ float scan32_add(float x) {
    x += dpp_f<0x111, 0xF>(0.f, x);
    x += dpp_f<0x112, 0xF>(0.f, x);
    x += dpp_f<0x114, 0xF>(0.f, x);
    x += dpp_f<0x118, 0xF>(0.f, x);
    x += dpp_f<0x142, 0xA>(0.f, x);
    return x;
}
__device__ __forceinline__ int scan32_max(int x) {
    x = max(x, dpp_i<0x111, 0xF>(-1, x));
    x = max(x, dpp_i<0x112, 0xF>(-1, x));
    x = max(x, dpp_i<0x114, 0xF>(-1, x));
    x = max(x, dpp_i<0x118, 0xF>(-1, x));
    x = max(x, dpp_i<0x142, 0xA>(-1, x));
    return x;
}
// broadcast lane 31 of each 32-half (ds_swizzle bit-mode: and=0, or=0x1F)
__device__ __forceinline__ float bcast31h(float x) {
    return __int_as_float(__builtin_amdgcn_ds_swizzle(__float_as_int(x), 0x03E0));
}

__device__ __forceinline__ float zof(int k) {   // iter-0 analytic z grid
    return 0.2f + 1.8f * ((float)k * (1.0f / 127.0f));
}

struct Ray { float ox, oy, oz, dx, dy, dz; };

__device__ __forceinline__ float sdf_at(const Ray& rr, float t) {
    float px = fminf(fmaxf(rr.ox + rr.dx * t, -1.f), 1.f);
    float py = fminf(fmaxf(rr.oy + rr.dy * t, -1.f), 1.f);
    float pz = fminf(fmaxf(rr.oz + rr.dz * t, -1.f), 1.f);
    return sqrtf(px * px + py * py + pz * pz) - 0.5f;
}

template<int IT>
__device__ __forceinline__ void run_iter(float2* __restrict__ zs, int* __restrict__ mk,
                                         float4* __restrict__ pl, float* __restrict__ outr,
                                         const int l, const Ray rr)
{
    constexpr int   N = 128 + 32 * IT;   // element count: 128,160,192,224
    constexpr int   R = N / 32;          // per-lane elements: 4,5,6,7 (exact)
    constexpr bool  LAST  = (IT == 3);
    constexpr bool  FIRST = (IT == 0);
    constexpr float H    = 1.8f / 127.0f;            // iter-0 uniform spacing
    constexpr float INVH = 1.0f / (H + 1e-5f);
    constexpr float c1   = -(float)(64 << IT) * 1.44269504f;  // exp2 scale: e^{-x*s}=2^{c1*x}
    constexpr float c05  = 0.5f * c1;
    constexpr float CH0  = c05 * H;
    const int k0 = l * R;

    // ---- owned elements (analytic on iter 0; packed LDS float2 otherwise) ----
    float ez[R], es[R];
    if constexpr (FIRST) {
        #pragma unroll
        for (int r = 0; r < R; ++r) { ez[r] = zof(k0 + r); es[r] = sdf_at(rr, ez[r]); }
    } else {
        #pragma unroll
        for (int r = 0; r < R; ++r) { float2 v = zs[k0 + r]; ez[r] = v.x; es[r] = v.y; }
    }
    // right neighbor = next lane's first element (lane31's top interval is out of
    // range by construction; every lane31 use below is guarded)
    const float zend = dpp_f<0x130, 0xF>(0.f, ez[0]);
    const float send = dpp_f<0x130, 0xF>(0.f, es[0]);

    // ---- cos of my last interval -> prev_cos for next lane's r=0 ----
    float ckL;
    if constexpr (FIRST) ckL = (send - es[R - 1]) * INVH;
    else                 ckL = __fdividef(send - es[R - 1], (zend - ez[R - 1]) + 1e-5f);
    float cosp = dpp_f<0x138, 0xF>(0.f, ckL);
    cosp = (l == 0) ? 0.f : cosp;                 // reference: prev_cos = 0 at k = 0

    // ---- alpha per interval (algebraic sigmoid: 2 exp2 + 1 div) -> q only ----
    float q[R];
    #pragma unroll
    for (int r = 0; r < R; ++r) {
        const float zk1 = (r == R - 1) ? zend : ez[r + 1];
        const float sk1 = (r == R - 1) ? send : es[r + 1];
        float ckr, chd;
        if constexpr (FIRST) {
            ckr = (sk1 - es[r]) * INVH;
            chd = CH0;
        } else {
            const float dz = zk1 - ez[r];
            ckr = __fdividef(sk1 - es[r], dz + 1e-5f);
            chd = c05 * dz;
        }
        const float cv = fmaxf(fminf(fminf(cosp, ckr), 0.0f), -1000.0f);
        const float c1mid = c05 * (es[r] + sk1);          // c1 * mid
        const float cvchd = cv * chd;                     // c1 * cv * hd
        const float A = __builtin_amdgcn_exp2f(fminf(c1mid - cvchd, 43.0f));
        const float B = __builtin_amdgcn_exp2f(fminf(c1mid + cvchd, 43.0f));
        const float A1 = 1.0f + A, B1 = 1.0f + B;
        const float prod = A1 * B1;
        const float al = __fdividef(fmaf(1e-5f, prod, B - A), fmaf(1e-5f, prod, B1));
        float qr = 1.0000001f - al;                       // (1 - al) + 1e-7
        if (r == R - 1) qr = (l == 31) ? 1.0f : qr;       // only invalid interval
        q[r] = qr;
        cosp = ckr;
    }

    // ---- exclusive transmittance cumprod (per-half DPP scan) ----
    float P = q[0];
    #pragma unroll
    for (int r = 1; r < R; ++r) P *= q[r];
    const float incP = scan32_mul(P);
    float T = dpp_f<0x138, 0xF>(1.f, incP);
    T = (l == 0) ? 1.0f : T;

    // ---- weights (recover a from q) + exclusive sum scan ----
    float wv[R], L = 0.f;
    #pragma unroll
    for (int r = 0; r < R; ++r) {
        const float a = 1.0000001f - q[r];
        float w_ = fmaf(a, T, 1e-5f);
        if (r == R - 1) w_ = (l == 31) ? 0.f : w_;
        wv[r] = w_;
        L += w_;
        T *= q[r];
    }
    const float incL = scan32_add(L);
    const float S = bcast31h(incL);
    float excL = dpp_f<0x138, 0xF>(0.f, incL);
    excL = (l == 0) ? 0.f : excL;

    // ---- FF pass: FF = 32*cdf + 0.4999999 ; cm = trunc(FF) = #{j: u_j < cdf} ----
    // (FF is also the sampling payload: t = ((l+1) - FF_l) / (FF_h - FF_l))
    const float g = 32.0f * (1.0f / S) * __fdividef(S, S);  // just 32/S
    float FF[R];
    int   cm[R];
    {
        const float g32 = __fdividef(32.0f, S);
        float run = excL;
        #pragma unroll
        for (int r = 0; r < R; ++r) {
            FF[r] = fmaf(run, g32, 0.49999994f);
            cm[r] = (int)FF[r];                   // FF >= 0.49 -> trunc == ceil(32c-0.5)
            run += wv[r];
        }
    }
    (void)g;
    const int   cmend = dpp_i<0x130, 0xF>(32, cm[0]);    // lane31 use is guarded
    const float FFend = dpp_f<0x130, 0xF>(33.f, FF[0]);  // lane31 use is guarded

    // ---- marks + payload: one store pair per nonempty interval ----
    #pragma unroll
    for (int r = 0; r < R; ++r) {
        const int jlo = cm[r];
        const int jhi = (r == R - 1) ? cmend : cm[r + 1];
        bool ne = (jhi > jlo);
        if (r == R - 1) ne = ne && (l != 31);
        if (ne) {
            const int   k   = k0 + r;
            const float ffh = (r == R - 1) ? FFend : FF[r + 1];
            float dzr;
            if constexpr (FIRST) dzr = H;
            else dzr = ((r == R - 1) ? zend : ez[r + 1]) - ez[r];
            mk[jlo] = (k << 5) | jlo;
            pl[jlo] = make_float4(FF[r], ffh, ez[r], dzr);
        }
    }
    wave_fence();   // marks + payload visible before sampling reads

    // ---- lane-parallel sampling: ALL 64 lanes (32 samples per ray half) ----
    int m0 = mk[l];
    if constexpr (!LAST) mk[l] = -1;   // same-lane same-address DS ops are ordered
    const int pack = scan32_max(m0);
    const int kk = pack >> 5, js = pack & 31;
    const float4 p4 = pl[js];          // {FF_l, FF_h, zk, dz}
    const float d = p4.y - p4.x;
    const float de = (d < 3.2e-4f) ? 32.0f : d;    // 32*(1e-5 normalized guard)
    const float t = __fdividef(((float)l + 1.0f) - p4.x, de);
    const float nz = fmaf(t, p4.w, p4.z);
    const int pos = kk + 1 + l;        // rank among old + stable index among new
    float ns = 0.f;
    if constexpr (!LAST) ns = sdf_at(rr, nz);

    // ---- in-place scatter (sampling read nothing from zs -> no fence needed) ----
    #pragma unroll
    for (int r = 0; r < R; ++r) {
        const int p = k0 + r + cm[r];
        if constexpr (LAST) { outr[p] = ez[r]; }
        else                { zs[p] = make_float2(ez[r], es[r]); }
    }
    if constexpr (LAST) { outr[pos] = nz; }
    else                { zs[pos] = make_float2(nz, ns); }

    if constexpr (!LAST) wave_fence();   // scatter drained before next iter's loads
}

__global__ __launch_bounds__(WPB * 64) void neus_kernel(
    const float* __restrict__ rays_o, const float* __restrict__ rays_d,
    float* __restrict__ out, int nrays)
{
    __shared__ __align__(16) float2 zsS[RPB][224];
    __shared__ __align__(16) float4 plS[RPB][32];
    __shared__               int    mkS[RPB][32];

    const int tid = threadIdx.x;
    const int rb  = tid >> 5;        // ray slot within block (one per 32-lane half)
    const int l   = tid & 31;        // lane within ray
    const int ray = blockIdx.x * RPB + rb;
    if (ray >= nrays) return;        // safe: no block-wide barriers anywhere

    float2* zs = zsS[rb];
    float4* pl = plS[rb];
    int*    mk = mkS[rb];

    Ray rr;
    rr.ox = rays_o[ray * 3 + 0]; rr.oy = rays_o[ray * 3 + 1]; rr.oz = rays_o[ray * 3 + 2];
    float rx = rays_d[ray * 3 + 0], ry = rays_d[ray * 3 + 1], rz = rays_d[ray * 3 + 2];
    float inv = __fdividef(1.0f, sqrtf(rx * rx + ry * ry + rz * rz) + 1e-8f);
    rr.dx = rx * inv; rr.dy = ry * inv; rr.dz = rz * inv;

    mk[l] = -1;   // drained by iter0's publish fence

    float* outr = out + (size_t)ray * 256;
    run_iter<0>(zs, mk, pl, outr, l, rr);   // fully analytic inputs
    run_iter<1>(zs, mk, pl, outr, l, rr);
    run_iter<2>(zs, mk, pl, outr, l, rr);
    run_iter<3>(zs, mk, pl, outr, l, rr);
}

extern "C" void kernel_launch(void* const* d_in, const int* in_sizes, int n_in,
                              void* d_out, int out_size, void* d_ws, size_t ws_size,
                              hipStream_t stream) {
    const float* rays_o = (const float*)d_in[0];
    const float* rays_d = (const float*)d_in[1];
    float* out = (float*)d_out;
    const int nrays = in_sizes[0] / 3;
    const int blocks = (nrays + RPB - 1) / RPB;
    neus_kernel<<<blocks, WPB * 64, 0, stream>>>(rays_o, rays_d, out, nrays);
}

// Round 9
// 90.870 us; speedup vs baseline: 1.1154x; 1.0296x over previous
//
#include <hip/hip_runtime.h>
#include <math.h>

#define WPB 4                 // waves per block
#define RPB (WPB * 2)         // 2 rays per wave (32 lanes each) -> 8 rays/block

// All per-ray LDS is touched only by its own wave (both halves belong to the wave).
__device__ __forceinline__ void wave_fence() {
    asm volatile("s_waitcnt lgkmcnt(0)" ::: "memory");
    __builtin_amdgcn_wave_barrier();
}

// DPP: row_shr:1/2/4/8 = 0x111/0x112/0x114/0x118, row_bcast15 = 0x142,
// wave_shl1 = 0x130 (lane i <- i+1), wave_shr1 = 0x138 (lane i <- i-1).
// bc=false keeps `ident` for invalid-source lanes; bc=true zero-fills (no ident mov).
template<int CTRL, int RMASK>
__device__ __forceinline__ float dpp_f(float ident, float x) {
    return __int_as_float(__builtin_amdgcn_update_dpp(
        __float_as_int(ident), __float_as_int(x), CTRL, RMASK, 0xF, false));
}
template<int CTRL, int RMASK>
__device__ __forceinline__ float dpp_f0(float x) {   // bc=1: invalid lanes -> 0
    return __int_as_float(__builtin_amdgcn_update_dpp(
        0, __float_as_int(x), CTRL, RMASK, 0xF, true));
}
template<int CTRL, int RMASK>
__device__ __forceinline__ int dpp_i0(int x) {       // bc=1: invalid lanes -> 0
    return __builtin_amdgcn_update_dpp(0, x, CTRL, RMASK, 0xF, true);
}
template<int CTRL, int RMASK>
__device__ __forceinline__ int dpp_i(int ident, int x) {
    return __builtin_amdgcn_update_dpp(ident, x, CTRL, RMASK, 0xF, false);
}

// 32-lane (per wave-half) inclusive scans.
// mul-scan: identity 1 requires bc=false ident movs.
__device__ __forceinline__ float scan32_mul(float x) {
    x *= dpp_f<0x111, 0xF>(1.f, x);
    x *= dpp_f<0x112, 0xF>(1.f, x);
    x *= dpp_f<0x114, 0xF>(1.f, x);
    x *= dpp_f<0x118, 0xF>(1.f, x);
    x *= dpp_f<0x142, 0xA>(1.f, x);
    return x;
}
// add-scan: identity 0 == bc=1 zero-fill; bcast15 step's masked-out rows add old=0.
__device__ __forceinline__ float scan32_add(float x) {
    x += dpp_f0<0x111, 0xF>(x);
    x += dpp_f0<0x112, 0xF>(x);
    x += dpp_f0<0x114, 0xF>(x);
    x += dpp_f0<0x118, 0xF>(x);
    x += dpp_f0<0x142, 0xA>(x);
    return x;
}
// max-scan over packed marks (all true values >= 0, so 0-fill never wins; the
// bcast15 step's masked-out rows take max(x, 0) = x since x >= 0 there).
__device__ __forceinline__ int scan32_max(int x) {
    x = max(x, dpp_i0<0x111, 0xF>(x));
    x = max(x, dpp_i0<0x112, 0xF>(x));
    x = max(x, dpp_i0<0x114, 0xF>(x));
    x = max(x, dpp_i0<0x118, 0xF>(x));
    x = max(x, dpp_i0<0x142, 0xA>(x));
    return x;
}
// broadcast lane 31 of each 32-half (ds_swizzle bit-mode: and=0, or=0x1F)
__device__ __forceinline__ float bcast31h(float x) {
    return __int_as_float(__builtin_amdgcn_ds_swizzle(__float_as_int(x), 0x03E0));
}

__device__ __forceinline__ float zof(int k) {   // iter-0 analytic z grid
    return 0.2f + 1.8f * ((float)k * (1.0f / 127.0f));
}

struct Ray { float ox, oy, oz, dx, dy, dz; };

__device__ __forceinline__ float sdf_at(const Ray& rr, float t) {
    float px = fminf(fmaxf(rr.ox + rr.dx * t, -1.f), 1.f);
    float py = fminf(fmaxf(rr.oy + rr.dy * t, -1.f), 1.f);
    float pz = fminf(fmaxf(rr.oz + rr.dz * t, -1.f), 1.f);
    return sqrtf(px * px + py * py + pz * pz) - 0.5f;
}

template<int IT>
__device__ __forceinline__ void run_iter(float2* __restrict__ zs, int* __restrict__ mk,
                                         float4* __restrict__ pl, float* __restrict__ outr,
                                         const int l, const Ray rr)
{
    constexpr int   N = 128 + 32 * IT;   // element count: 128,160,192,224
    constexpr int   R = N / 32;          // per-lane elements: 4,5,6,7 (exact)
    constexpr bool  LAST  = (IT == 3);
    constexpr bool  FIRST = (IT == 0);
    constexpr float H    = 1.8f / 127.0f;            // iter-0 uniform spacing
    constexpr float INVH = 1.0f / (H + 1e-5f);
    constexpr float c1   = -(float)(64 << IT) * 1.44269504f;  // e^{-x*s} = 2^{c1*x}
    constexpr float c05  = 0.5f * c1;
    constexpr float CH0  = c05 * H;
    constexpr int   TAG  = IT << 13;     // current-iter marks dominate stale ones
    const int k0 = l * R;

    // ---- owned elements (analytic on iter 0; packed LDS float2 otherwise) ----
    float ez[R], es[R];
    if constexpr (FIRST) {
        #pragma unroll
        for (int r = 0; r < R; ++r) { ez[r] = zof(k0 + r); es[r] = sdf_at(rr, ez[r]); }
    } else {
        #pragma unroll
        for (int r = 0; r < R; ++r) { float2 v = zs[k0 + r]; ez[r] = v.x; es[r] = v.y; }
    }
    // right neighbor = next lane's first element (lane31's top interval is out of
    // range by construction; every lane31 use below is guarded)
    const float zend = dpp_f<0x130, 0xF>(0.f, ez[0]);
    const float send = dpp_f<0x130, 0xF>(0.f, es[0]);

    // ---- cos of my last interval -> prev_cos for next lane's r=0 ----
    float ckL;
    if constexpr (FIRST) ckL = (send - es[R - 1]) * INVH;
    else                 ckL = __fdividef(send - es[R - 1], (zend - ez[R - 1]) + 1e-5f);
    float cosp = dpp_f0<0x138, 0xF>(ckL);         // lane0 -> 0 via bc=1
    cosp = (l == 0) ? 0.f : cosp;                 // lane32 cross-half leak fix

    // ---- alpha per interval (algebraic sigmoid: 2 exp2 + 1 div) ----
    float al[R], q[R];
    #pragma unroll
    for (int r = 0; r < R; ++r) {
        const float zk1 = (r == R - 1) ? zend : ez[r + 1];
        const float sk1 = (r == R - 1) ? send : es[r + 1];
        float ckr, chd;
        if constexpr (FIRST) {
            ckr = (sk1 - es[r]) * INVH;
            chd = CH0;
        } else {
            const float dz = zk1 - ez[r];
            ckr = __fdividef(sk1 - es[r], dz + 1e-5f);
            chd = c05 * dz;
        }
        const float cv = fmaxf(fminf(fminf(cosp, ckr), 0.0f), -1000.0f);
        const float c1mid = c05 * (es[r] + sk1);          // c1 * mid
        const float cvchd = cv * chd;                     // c1 * cv * hd
        const float A = __builtin_amdgcn_exp2f(fminf(c1mid - cvchd, 43.0f));
        const float B = __builtin_amdgcn_exp2f(fminf(c1mid + cvchd, 43.0f));
        const float A1 = 1.0f + A, B1 = 1.0f + B;
        const float prod = A1 * B1;
        float a_ = __fdividef(fmaf(1e-5f, prod, B - A), fmaf(1e-5f, prod, B1));
        al[r] = a_;
        float qr = 1.0000001f - a_;                       // (1 - al) + 1e-7
        if (r == R - 1) qr = (l == 31) ? 1.0f : qr;       // only invalid interval
        q[r] = qr;
        cosp = ckr;
    }

    // ---- exclusive transmittance cumprod (per-half DPP scan) ----
    float P = q[0];
    #pragma unroll
    for (int r = 1; r < R; ++r) P *= q[r];
    const float incP = scan32_mul(P);
    float T = dpp_f<0x138, 0xF>(1.f, incP);
    T = (l == 0) ? 1.0f : T;

    // ---- weights (al reused) + exclusive sum scan ----
    float wv[R], L = 0.f;
    #pragma unroll
    for (int r = 0; r < R; ++r) {
        float w_ = fmaf(al[r], T, 1e-5f);
        if (r == R - 1) w_ = (l == 31) ? 0.f : w_;
        wv[r] = w_;
        L += w_;
        T *= q[r];
    }
    const float incL = scan32_add(L);
    const float S = bcast31h(incL);
    float excL = dpp_f0<0x138, 0xF>(incL);        // lane0 -> 0 via bc=1
    excL = (l == 0) ? 0.f : excL;                 // lane32 cross-half leak fix

    // ---- FF pass: FF = 32*cdf + 0.4999999 ; cm = trunc(FF) = #{j: u_j < cdf} ----
    // (FF is also the sampling payload: t = ((l+1) - FF_l) / (FF_h - FF_l))
    float FF[R];
    int   cm[R];
    {
        const float g32 = __fdividef(32.0f, S);
        float run = excL;
        #pragma unroll
        for (int r = 0; r < R; ++r) {
            FF[r] = fmaf(run, g32, 0.49999994f);
            cm[r] = (int)FF[r];                   // FF >= 0.49 -> trunc == ceil(32c-0.5)
            run += wv[r];
        }
    }
    const int   cmend = dpp_i<0x130, 0xF>(32, cm[0]);    // lane31 use is guarded
    const float FFend = dpp_f<0x130, 0xF>(33.f, FF[0]);  // lane31 use is guarded

    // ---- marks + payload: one store pair per nonempty interval ----
    #pragma unroll
    for (int r = 0; r < R; ++r) {
        const int jlo = cm[r];
        const int jhi = (r == R - 1) ? cmend : cm[r + 1];
        bool ne = (jhi > jlo);
        if (r == R - 1) ne = ne && (l != 31);
        if (ne) {
            const int   k   = k0 + r;
            const float ffh = (r == R - 1) ? FFend : FF[r + 1];
            float dzr;
            if constexpr (FIRST) dzr = H;
            else dzr = ((r == R - 1) ? zend : ez[r + 1]) - ez[r];
            mk[jlo] = TAG | (k << 5) | jlo;
            pl[jlo] = make_float4(FF[r], ffh, ez[r], dzr);
        }
    }
    wave_fence();   // marks + payload visible before sampling reads

    // ---- lane-parallel sampling: ALL 64 lanes (32 samples per ray half) ----
    // Stale marks (smaller TAG) always lose the max-scan -> no per-iter clears.
    const int pack = scan32_max(mk[l]);
    const int kk = (pack >> 5) & 0xFF, js = pack & 31;
    const float4 p4 = pl[js];          // {FF_l, FF_h, zk, dz}
    const float d = p4.y - p4.x;
    const float de = (d < 3.2e-4f) ? 32.0f : d;    // 32*(1e-5 normalized guard)
    const float t = __fdividef(((float)l + 1.0f) - p4.x, de);
    const float nz = fmaf(t, p4.w, p4.z);
    const int pos = kk + 1 + l;        // rank among old + stable index among new
    float ns = 0.f;
    if constexpr (!LAST) ns = sdf_at(rr, nz);

    // ---- in-place scatter (sampling read nothing from zs -> no fence needed) ----
    #pragma unroll
    for (int r = 0; r < R; ++r) {
        const int p = k0 + r + cm[r];
        if constexpr (LAST) { outr[p] = ez[r]; }
        else                { zs[p] = make_float2(ez[r], es[r]); }
    }
    if constexpr (LAST) { outr[pos] = nz; }
    else                { zs[pos] = make_float2(nz, ns); }

    if constexpr (!LAST) wave_fence();   // scatter drained before next iter's loads
}

__global__ __launch_bounds__(WPB * 64) void neus_kernel(
    const float* __restrict__ rays_o, const float* __restrict__ rays_d,
    float* __restrict__ out, int nrays)
{
    __shared__ __align__(16) float2 zsS[RPB][224];
    __shared__ __align__(16) float4 plS[RPB][32];
    __shared__               int    mkS[RPB][32];

    const int tid = threadIdx.x;
    const int rb  = tid >> 5;        // ray slot within block (one per 32-lane half)
    const int l   = tid & 31;        // lane within ray
    const int ray = blockIdx.x * RPB + rb;
    if (ray >= nrays) return;        // safe: no block-wide barriers anywhere

    float2* zs = zsS[rb];
    float4* pl = plS[rb];
    int*    mk = mkS[rb];

    Ray rr;
    rr.ox = rays_o[ray * 3 + 0]; rr.oy = rays_o[ray * 3 + 1]; rr.oz = rays_o[ray * 3 + 2];
    float rx = rays_d[ray * 3 + 0], ry = rays_d[ray * 3 + 1], rz = rays_d[ray * 3 + 2];
    float inv = __fdividef(1.0f, sqrtf(rx * rx + ry * ry + rz * rz) + 1e-8f);
    rr.dx = rx * inv; rr.dy = ry * inv; rr.dz = rz * inv;

    mk[l] = -1;   // one-time garbage guard (uninitialized LDS); drained by iter0 fence

    float* outr = out + (size_t)ray * 256;
    run_iter<0>(zs, mk, pl, outr, l, rr);   // fully analytic inputs
    run_iter<1>(zs, mk, pl, outr, l, rr);
    run_iter<2>(zs, mk, pl, outr, l, rr);
    run_iter<3>(zs, mk, pl, outr, l, rr);
}

extern "C" void kernel_launch(void* const* d_in, const int* in_sizes, int n_in,
                              void* d_out, int out_size, void* d_ws, size_t ws_size,
                              hipStream_t stream) {
    const float* rays_o = (const float*)d_in[0];
    const float* rays_d = (const float*)d_in[1];
    float* out = (float*)d_out;
    const int nrays = in_sizes[0] / 3;
    const int blocks = (nrays + RPB - 1) / RPB;
    neus_kernel<<<blocks, WPB * 64, 0, stream>>>(rays_o, rays_d, out, nrays);
}